// Round 4
// baseline (433.518 us; speedup 1.0000x reference)
//
#include <hip/hip_runtime.h>

#define NC 14
#define DIM 96
#define PP (DIM*DIM*DIM)          // 884736 voxels per batch
#define VPT 8                     // voxels per thread (consecutive d, 32B-aligned)
#define VPB (256*VPT)             // 2048 voxels per block
#define BLOCKS_PER_B (PP/VPB)     // 432 blocks per batch

// Class-major sweep: per thread, loop classes 0..13 loading 32B of T and 32B of S
// per class (contiguous within one class-plane) -> a wave touches ONE plane region
// at a time (2KB contiguous) instead of interleaving 28 strided streams.
__global__ __launch_bounds__(256, 4) void bkd_main(
    const float* __restrict__ S, const float* __restrict__ T,
    const int* __restrict__ lab,
    double* __restrict__ gnum, int* __restrict__ gcnt)
{
    const int tid = threadIdx.x;
    const unsigned bq = blockIdx.x;
    const unsigned b  = bq / BLOCKS_PER_B;                 // 0/1, block-uniform
    const int p = (int)((bq - b * BLOCKS_PER_B) * VPB) + tid * VPT;
    const int d = p % DIM;                                 // multiple of 8
    const int t = p / DIM;
    const int w = t % DIM;
    const int h = t / DIM;

    const float* Tb = T + (size_t)b * NC * PP + p;
    const float* Sb = S + (size_t)b * NC * PP + p;

    float ZT[VPT], ZS[VPT], A[VPT];
#pragma unroll
    for (int i = 0; i < VPT; ++i) { ZT[i] = 0.f; ZS[i] = 0.f; A[i] = 0.f; }

    const int rot = (int)(bq % NC);                        // block-uniform class rotation
#pragma unroll
    for (int cc = 0; cc < NC; ++cc) {
        int c = cc + rot; if (c >= NC) c -= NC;
        const size_t off = (size_t)c * PP;
        const float4 t0 = *(const float4*)(Tb + off);
        const float4 t1 = *(const float4*)(Tb + off + 4);
        const float4 s0 = *(const float4*)(Sb + off);
        const float4 s1 = *(const float4*)(Sb + off + 4);
        const float tv[VPT] = {t0.x, t0.y, t0.z, t0.w, t1.x, t1.y, t1.z, t1.w};
        const float sv[VPT] = {s0.x, s0.y, s0.z, s0.w, s1.x, s1.y, s1.z, s1.w};
#pragma unroll
        for (int i = 0; i < VPT; ++i) {
            const float u = __expf(tv[i]);
            ZT[i] += u;
            ZS[i] += __expf(sv[i]);
            A[i]   = fmaf(u, tv[i] - sv[i], A[i]);
        }
    }

    float kl[VPT];
#pragma unroll
    for (int i = 0; i < VPT; ++i)
        kl[i] = A[i] / ZT[i] + __logf(ZS[i]) - __logf(ZT[i]);

    // ---- neighbor-label distinct-class masks for the 8 voxels ----
    const int lbase = (int)b * PP;
    unsigned mk[VPT];
#pragma unroll
    for (int i = 0; i < VPT; ++i) mk[i] = 0u;

#pragma unroll
    for (int dh = -1; dh <= 1; ++dh) {
        const int hh = h + dh;
        if ((unsigned)hh >= (unsigned)DIM) continue;
#pragma unroll
        for (int dw = -1; dw <= 1; ++dw) {
            const int ww = w + dw;
            if ((unsigned)ww >= (unsigned)DIM) continue;
            const int* rp = lab + lbase + (hh * DIM + ww) * DIM + d;
            const int4 v0 = *(const int4*)rp;
            const int4 v1 = *(const int4*)(rp + 4);
            unsigned lb[VPT + 2];                    // bits of labels at d-1 .. d+8
            lb[0] = (d > 0)       ? (1u << rp[-1]) : 0u;
            lb[1] = 1u << v0.x;  lb[2] = 1u << v0.y;
            lb[3] = 1u << v0.z;  lb[4] = 1u << v0.w;
            lb[5] = 1u << v1.x;  lb[6] = 1u << v1.y;
            lb[7] = 1u << v1.z;  lb[8] = 1u << v1.w;
            lb[9] = (d < DIM - VPT) ? (1u << rp[VPT]) : 0u;
            if (dh == 0 && dw == 0) {                // center row: exclude own voxel
#pragma unroll
                for (int i = 0; i < VPT; ++i) mk[i] |= lb[i] | lb[i + 2];
            } else {
#pragma unroll
                for (int i = 0; i < VPT; ++i) mk[i] |= lb[i] | lb[i + 1] | lb[i + 2];
            }
        }
    }

    // interior voxel with a single distinct neighbor class contributes nothing
    const bool hwi = (h >= 1 && h <= DIM - 2 && w >= 1 && w <= DIM - 2);
#pragma unroll
    for (int i = 0; i < VPT; ++i) {
        const int dd = d + i;
        const bool din = (dd > 0) && (dd < DIM - 1);
        if (hwi && din && (mk[i] & (mk[i] - 1)) == 0u) mk[i] = 0u;
    }

    // ---- per-class accumulate (registers) ----
    float lnum[NC];
    int   lcnt[NC];
#pragma unroll
    for (int k = 0; k < NC; ++k) { lnum[k] = 0.f; lcnt[k] = 0; }
#pragma unroll
    for (int i = 0; i < VPT; ++i) {
        const float kv = kl[i];
        const unsigned mm = mk[i];
#pragma unroll
        for (int k = 0; k < NC; ++k) {
            lnum[k] += (mm & (1u << k)) ? kv : 0.f;
            lcnt[k] += (mm >> k) & 1u;
        }
    }

    // ---- wave (64-lane) shuffle reduction ----
#pragma unroll
    for (int k = 0; k < NC; ++k) {
        float v = lnum[k];
        int   c = lcnt[k];
#pragma unroll
        for (int off = 32; off > 0; off >>= 1) {
            v += __shfl_down(v, off, 64);
            c += __shfl_down(c, off, 64);
        }
        lnum[k] = v; lcnt[k] = c;
    }

    __shared__ float s_num[NC];
    __shared__ int   s_cnt[NC];
    if (tid < NC) { s_num[tid] = 0.f; s_cnt[tid] = 0; }
    __syncthreads();
    if ((tid & 63) == 0) {
#pragma unroll
        for (int k = 0; k < NC; ++k) {
            atomicAdd(&s_num[k], lnum[k]);
            atomicAdd(&s_cnt[k], lcnt[k]);
        }
    }
    __syncthreads();
    if (tid < NC) {
        atomicAdd(&gnum[b * NC + tid], (double)s_num[tid]);
        atomicAdd(&gcnt[b * NC + tid], s_cnt[tid]);
    }
}

__global__ void bkd_final(const double* __restrict__ gnum,
                          const int* __restrict__ gcnt,
                          float* __restrict__ out)
{
    const int i = threadIdx.x;            // one block of 64 threads
    double term = 0.0;
    if (i < 2 * NC) {
        const int c = gcnt[i];
        if (c > 0) term = gnum[i] / ((double)NC * (double)c);
    }
#pragma unroll
    for (int off = 32; off > 0; off >>= 1)
        term += __shfl_down(term, off, 64);
    if (i == 0) out[0] = (float)term;
}

extern "C" void kernel_launch(void* const* d_in, const int* in_sizes, int n_in,
                              void* d_out, int out_size, void* d_ws, size_t ws_size,
                              hipStream_t stream) {
    const float* S  = (const float*)d_in[0];   // preds_S [2,14,96,96,96] f32
    const float* T  = (const float*)d_in[1];   // preds_T [2,14,96,96,96] f32
    const int* lab  = (const int*)d_in[2];     // gt_labels [2,1,96,96,96] int32
    float* out      = (float*)d_out;

    double* gnum = (double*)d_ws;                                   // [2*14]
    int*    gcnt = (int*)((char*)d_ws + 2 * NC * sizeof(double));   // [2*14]

    hipMemsetAsync(d_ws, 0, 2 * NC * (sizeof(double) + sizeof(int)), stream);

    bkd_main<<<2 * BLOCKS_PER_B, 256, 0, stream>>>(S, T, lab, gnum, gcnt);
    bkd_final<<<1, 64, 0, stream>>>(gnum, gcnt, out);
}

// Round 5
// 251.303 us; speedup vs baseline: 1.7251x; 1.7251x over previous
//
#include <hip/hip_runtime.h>

#define NC 14
#define DIM 96
#define PP (DIM*DIM*DIM)          // 884736 voxels per batch
#define VPT 4                     // voxels per thread (consecutive d, 16B-aligned)
#define VPB (256*VPT)             // 1024 voxels per block
#define BLOCKS_PER_B (PP/VPB)     // 864 blocks per batch

// Class-major sweep (R4's contiguous-stream pattern) with R2's register budget:
// VPT=4, scalar accumulators, software-pipelined class loop, no VGPR cap.
// Each block reads a contiguous 4KB window per class-plane -> DRAM row/TLB
// locality; per-CU MSHR-limited BW improves ~3x vs voxel-major interleave.
__global__ __launch_bounds__(256) void bkd_main(
    const float* __restrict__ S, const float* __restrict__ T,
    const int* __restrict__ lab,
    double* __restrict__ gnum, int* __restrict__ gcnt)
{
    const int tid = threadIdx.x;
    const unsigned bq = blockIdx.x;
    const unsigned b  = bq / BLOCKS_PER_B;                 // 0/1, block-uniform
    const int p = (int)((bq - b * BLOCKS_PER_B) * VPB) + tid * VPT;
    const int d = p % DIM;                                 // multiple of 4
    const int t = p / DIM;
    const int w = t % DIM;
    const int h = t / DIM;

    const float* Tb = T + (size_t)b * NC * PP + p;
    const float* Sb = S + (size_t)b * NC * PP + p;

    float ZT0=0,ZT1=0,ZT2=0,ZT3=0, ZS0=0,ZS1=0,ZS2=0,ZS3=0, A0=0,A1=0,A2=0,A3=0;

    // software-pipelined class-major loop: prefetch class c+1 while reducing c
    float4 t4 = *(const float4*)(Tb);
    float4 s4 = *(const float4*)(Sb);
#pragma unroll
    for (int c = 0; c < NC; ++c) {
        float4 tn, sn;
        if (c < NC - 1) {
            tn = *(const float4*)(Tb + (size_t)(c + 1) * PP);
            sn = *(const float4*)(Sb + (size_t)(c + 1) * PP);
        }
        const float u0 = __expf(t4.x), u1 = __expf(t4.y),
                    u2 = __expf(t4.z), u3 = __expf(t4.w);
        ZT0 += u0; ZT1 += u1; ZT2 += u2; ZT3 += u3;
        ZS0 += __expf(s4.x); ZS1 += __expf(s4.y);
        ZS2 += __expf(s4.z); ZS3 += __expf(s4.w);
        A0 = fmaf(u0, t4.x - s4.x, A0);
        A1 = fmaf(u1, t4.y - s4.y, A1);
        A2 = fmaf(u2, t4.z - s4.z, A2);
        A3 = fmaf(u3, t4.w - s4.w, A3);
        t4 = tn; s4 = sn;
    }
    const float kl0 = A0 / ZT0 + __logf(ZS0) - __logf(ZT0);
    const float kl1 = A1 / ZT1 + __logf(ZS1) - __logf(ZT1);
    const float kl2 = A2 / ZT2 + __logf(ZS2) - __logf(ZT2);
    const float kl3 = A3 / ZT3 + __logf(ZS3) - __logf(ZT3);

    // ---- neighbor-label distinct-class masks (R2's compact scheme) ----
    const int lbase = (int)b * PP;
    unsigned m0 = 0, m1 = 0, m2 = 0, m3 = 0;
#pragma unroll
    for (int dh = -1; dh <= 1; ++dh) {
        const int hh = h + dh;
        if ((unsigned)hh >= (unsigned)DIM) continue;
#pragma unroll
        for (int dw = -1; dw <= 1; ++dw) {
            const int ww = w + dw;
            if ((unsigned)ww >= (unsigned)DIM) continue;
            const int* rp = lab + lbase + (hh * DIM + ww) * DIM + d;
            const int4 v = *(const int4*)rp;            // labels at d..d+3 (16B aligned)
            const unsigned a0 = 1u << v.x, a1 = 1u << v.y, a2 = 1u << v.z, a3 = 1u << v.w;
            const unsigned mla = (d > 0)        ? (1u << rp[-1]) : 0u;
            const unsigned mlb = (d < DIM - 4)  ? (1u << rp[4])  : 0u;
            if (dh == 0 && dw == 0) {                   // center row: exclude own voxel
                m0 |= mla | a1;  m1 |= a0 | a2;  m2 |= a1 | a3;  m3 |= a2 | mlb;
            } else {
                const unsigned s01 = a0 | a1, s12 = a1 | a2, s23 = a2 | a3;
                m0 |= mla | s01;  m1 |= s01 | a2;  m2 |= s12 | a3;  m3 |= s23 | mlb;
            }
        }
    }

    // interior voxel whose 26 neighbors are all one class contributes nothing
    const bool hwi = (h >= 1 && h <= DIM - 2 && w >= 1 && w <= DIM - 2);
    const unsigned mc0 = (hwi && d > 0       && (m0 & (m0 - 1)) == 0) ? 0u : m0;
    const unsigned mc1 = (hwi                && (m1 & (m1 - 1)) == 0) ? 0u : m1;
    const unsigned mc2 = (hwi                && (m2 & (m2 - 1)) == 0) ? 0u : m2;
    const unsigned mc3 = (hwi && d < DIM - 4 && (m3 & (m3 - 1)) == 0) ? 0u : m3;

    // ---- per-class accumulate (fully unrolled -> registers) ----
    float lnum[NC];
    int   lcnt[NC];
#pragma unroll
    for (int k = 0; k < NC; ++k) {
        const unsigned bit = 1u << k;
        lcnt[k] = ((mc0 & bit) ? 1 : 0) + ((mc1 & bit) ? 1 : 0)
                + ((mc2 & bit) ? 1 : 0) + ((mc3 & bit) ? 1 : 0);
        lnum[k] = ((mc0 & bit) ? kl0 : 0.f) + ((mc1 & bit) ? kl1 : 0.f)
                + ((mc2 & bit) ? kl2 : 0.f) + ((mc3 & bit) ? kl3 : 0.f);
    }

    // ---- wave (64-lane) shuffle reduction ----
#pragma unroll
    for (int k = 0; k < NC; ++k) {
        float v = lnum[k];
        int   c = lcnt[k];
#pragma unroll
        for (int off = 32; off > 0; off >>= 1) {
            v += __shfl_down(v, off, 64);
            c += __shfl_down(c, off, 64);
        }
        lnum[k] = v; lcnt[k] = c;
    }

    __shared__ float s_num[NC];
    __shared__ int   s_cnt[NC];
    if (tid < NC) { s_num[tid] = 0.f; s_cnt[tid] = 0; }
    __syncthreads();
    if ((tid & 63) == 0) {
#pragma unroll
        for (int k = 0; k < NC; ++k) {
            atomicAdd(&s_num[k], lnum[k]);
            atomicAdd(&s_cnt[k], lcnt[k]);
        }
    }
    __syncthreads();
    if (tid < NC) {
        atomicAdd(&gnum[b * NC + tid], (double)s_num[tid]);
        atomicAdd(&gcnt[b * NC + tid], s_cnt[tid]);
    }
}

__global__ void bkd_final(const double* __restrict__ gnum,
                          const int* __restrict__ gcnt,
                          float* __restrict__ out)
{
    const int i = threadIdx.x;            // one block of 64 threads
    double term = 0.0;
    if (i < 2 * NC) {
        const int c = gcnt[i];
        if (c > 0) term = gnum[i] / ((double)NC * (double)c);
    }
#pragma unroll
    for (int off = 32; off > 0; off >>= 1)
        term += __shfl_down(term, off, 64);
    if (i == 0) out[0] = (float)term;
}

extern "C" void kernel_launch(void* const* d_in, const int* in_sizes, int n_in,
                              void* d_out, int out_size, void* d_ws, size_t ws_size,
                              hipStream_t stream) {
    const float* S  = (const float*)d_in[0];   // preds_S [2,14,96,96,96] f32
    const float* T  = (const float*)d_in[1];   // preds_T [2,14,96,96,96] f32
    const int* lab  = (const int*)d_in[2];     // gt_labels [2,1,96,96,96] int32
    float* out      = (float*)d_out;

    double* gnum = (double*)d_ws;                                   // [2*14]
    int*    gcnt = (int*)((char*)d_ws + 2 * NC * sizeof(double));   // [2*14]

    hipMemsetAsync(d_ws, 0, 2 * NC * (sizeof(double) + sizeof(int)), stream);

    bkd_main<<<2 * BLOCKS_PER_B, 256, 0, stream>>>(S, T, lab, gnum, gcnt);
    bkd_final<<<1, 64, 0, stream>>>(gnum, gcnt, out);
}

// Round 6
// 238.678 us; speedup vs baseline: 1.8163x; 1.0529x over previous
//
#include <hip/hip_runtime.h>

#define NC 14
#define DIM 96
#define PP (DIM*DIM*DIM)          // 884736 voxels per batch
#define VPT 8                     // voxels per thread (consecutive d, 32B-aligned)
#define VPB (256*VPT)             // 2048 voxels per block
#define BLOCKS_PER_B (PP/VPB)     // 432 blocks per batch

// Class-SEQUENTIAL sweep, genuinely rolled: at any instant a block has loads in
// flight from only ~2 class-planes (current math + 1-deep prefetch) instead of
// all 28 -> concurrent translation working set ~8-12 pages per block (fits
// UTCL1) vs ~60-110 in R1-R5 (thrash -> the ~1 TB/s wall).
__global__ __launch_bounds__(256) void bkd_main(
    const float* __restrict__ S, const float* __restrict__ T,
    const int* __restrict__ lab,
    double* __restrict__ gnum, int* __restrict__ gcnt)
{
    const int tid = threadIdx.x;
    const unsigned bq = blockIdx.x;
    const unsigned b  = bq / BLOCKS_PER_B;                 // 0/1, block-uniform
    const int p = (int)((bq - b * BLOCKS_PER_B) * VPB) + tid * VPT;
    const int d = p % DIM;                                 // multiple of 8
    const int t = p / DIM;
    const int w = t % DIM;
    const int h = t / DIM;

    const float* tp = T + (size_t)b * NC * PP + p;
    const float* sp = S + (size_t)b * NC * PP + p;

    float ZT[VPT], ZS[VPT], A[VPT];
#pragma unroll
    for (int i = 0; i < VPT; ++i) { ZT[i] = 0.f; ZS[i] = 0.f; A[i] = 0.f; }

    // prefetch class 0
    float4 t0 = *(const float4*)(tp);
    float4 t1 = *(const float4*)(tp + 4);
    float4 s0 = *(const float4*)(sp);
    float4 s1 = *(const float4*)(sp + 4);

#define CONSUME()                                                            \
    {                                                                        \
        const float tv[VPT] = {t0.x, t0.y, t0.z, t0.w, t1.x, t1.y, t1.z, t1.w}; \
        const float sv[VPT] = {s0.x, s0.y, s0.z, s0.w, s1.x, s1.y, s1.z, s1.w}; \
        _Pragma("unroll")                                                    \
        for (int i = 0; i < VPT; ++i) {                                      \
            const float u = __expf(tv[i]);                                   \
            ZT[i] += u;                                                      \
            ZS[i] += __expf(sv[i]);                                          \
            A[i]   = fmaf(u, tv[i] - sv[i], A[i]);                           \
        }                                                                    \
    }

#pragma unroll 1
    for (int c = 0; c < NC - 1; ++c) {
        // issue next class's loads (independent of current math)
        const float* tpn = tp + PP;
        const float* spn = sp + PP;
        const float4 nt0 = *(const float4*)(tpn);
        const float4 nt1 = *(const float4*)(tpn + 4);
        const float4 ns0 = *(const float4*)(spn);
        const float4 ns1 = *(const float4*)(spn + 4);
        CONSUME();
        tp = tpn; sp = spn;
        t0 = nt0; t1 = nt1; s0 = ns0; s1 = ns1;
    }
    CONSUME();    // class NC-1 (peeled)
#undef CONSUME

    float kl[VPT];
#pragma unroll
    for (int i = 0; i < VPT; ++i)
        kl[i] = A[i] / ZT[i] + __logf(ZS[i]) - __logf(ZT[i]);

    // ---- neighbor-label distinct-class masks (R4's verified VPT=8 logic) ----
    const int lbase = (int)b * PP;
    unsigned mk[VPT];
#pragma unroll
    for (int i = 0; i < VPT; ++i) mk[i] = 0u;

#pragma unroll
    for (int dh = -1; dh <= 1; ++dh) {
        const int hh = h + dh;
        if ((unsigned)hh >= (unsigned)DIM) continue;
#pragma unroll
        for (int dw = -1; dw <= 1; ++dw) {
            const int ww = w + dw;
            if ((unsigned)ww >= (unsigned)DIM) continue;
            const int* rp = lab + lbase + (hh * DIM + ww) * DIM + d;
            const int4 v0 = *(const int4*)rp;
            const int4 v1 = *(const int4*)(rp + 4);
            unsigned lb[VPT + 2];                    // label bits at d-1 .. d+8
            lb[0] = (d > 0)         ? (1u << rp[-1])  : 0u;
            lb[1] = 1u << v0.x;  lb[2] = 1u << v0.y;
            lb[3] = 1u << v0.z;  lb[4] = 1u << v0.w;
            lb[5] = 1u << v1.x;  lb[6] = 1u << v1.y;
            lb[7] = 1u << v1.z;  lb[8] = 1u << v1.w;
            lb[9] = (d < DIM - VPT) ? (1u << rp[VPT]) : 0u;
            if (dh == 0 && dw == 0) {                // center row: exclude own voxel
#pragma unroll
                for (int i = 0; i < VPT; ++i) mk[i] |= lb[i] | lb[i + 2];
            } else {
#pragma unroll
                for (int i = 0; i < VPT; ++i) mk[i] |= lb[i] | lb[i + 1] | lb[i + 2];
            }
        }
    }

    // interior voxel with a single distinct neighbor class contributes nothing
    const bool hwi = (h >= 1 && h <= DIM - 2 && w >= 1 && w <= DIM - 2);
#pragma unroll
    for (int i = 0; i < VPT; ++i) {
        const int dd = d + i;
        const bool din = (dd > 0) && (dd < DIM - 1);
        if (hwi && din && (mk[i] & (mk[i] - 1)) == 0u) mk[i] = 0u;
    }

    // ---- per-class accumulate (registers) ----
    float lnum[NC];
    int   lcnt[NC];
#pragma unroll
    for (int k = 0; k < NC; ++k) { lnum[k] = 0.f; lcnt[k] = 0; }
#pragma unroll
    for (int i = 0; i < VPT; ++i) {
        const float kv = kl[i];
        const unsigned mm = mk[i];
#pragma unroll
        for (int k = 0; k < NC; ++k) {
            lnum[k] += (mm & (1u << k)) ? kv : 0.f;
            lcnt[k] += (mm >> k) & 1u;
        }
    }

    // ---- wave (64-lane) shuffle reduction ----
#pragma unroll
    for (int k = 0; k < NC; ++k) {
        float v = lnum[k];
        int   c = lcnt[k];
#pragma unroll
        for (int off = 32; off > 0; off >>= 1) {
            v += __shfl_down(v, off, 64);
            c += __shfl_down(c, off, 64);
        }
        lnum[k] = v; lcnt[k] = c;
    }

    __shared__ float s_num[NC];
    __shared__ int   s_cnt[NC];
    if (tid < NC) { s_num[tid] = 0.f; s_cnt[tid] = 0; }
    __syncthreads();
    if ((tid & 63) == 0) {
#pragma unroll
        for (int k = 0; k < NC; ++k) {
            atomicAdd(&s_num[k], lnum[k]);
            atomicAdd(&s_cnt[k], lcnt[k]);
        }
    }
    __syncthreads();
    if (tid < NC) {
        atomicAdd(&gnum[b * NC + tid], (double)s_num[tid]);
        atomicAdd(&gcnt[b * NC + tid], s_cnt[tid]);
    }
}

__global__ void bkd_final(const double* __restrict__ gnum,
                          const int* __restrict__ gcnt,
                          float* __restrict__ out)
{
    const int i = threadIdx.x;            // one block of 64 threads
    double term = 0.0;
    if (i < 2 * NC) {
        const int c = gcnt[i];
        if (c > 0) term = gnum[i] / ((double)NC * (double)c);
    }
#pragma unroll
    for (int off = 32; off > 0; off >>= 1)
        term += __shfl_down(term, off, 64);
    if (i == 0) out[0] = (float)term;
}

extern "C" void kernel_launch(void* const* d_in, const int* in_sizes, int n_in,
                              void* d_out, int out_size, void* d_ws, size_t ws_size,
                              hipStream_t stream) {
    const float* S  = (const float*)d_in[0];   // preds_S [2,14,96,96,96] f32
    const float* T  = (const float*)d_in[1];   // preds_T [2,14,96,96,96] f32
    const int* lab  = (const int*)d_in[2];     // gt_labels [2,1,96,96,96] int32
    float* out      = (float*)d_out;

    double* gnum = (double*)d_ws;                                   // [2*14]
    int*    gcnt = (int*)((char*)d_ws + 2 * NC * sizeof(double));   // [2*14]

    hipMemsetAsync(d_ws, 0, 2 * NC * (sizeof(double) + sizeof(int)), stream);

    bkd_main<<<2 * BLOCKS_PER_B, 256, 0, stream>>>(S, T, lab, gnum, gcnt);
    bkd_final<<<1, 64, 0, stream>>>(gnum, gcnt, out);
}